// Round 9
// baseline (112.069 us; speedup 1.0000x reference)
//
#include <hip/hip_runtime.h>
#include <hip/hip_bf16.h>

// AttentivePooling: B=32, S=8192, C=256, MID=128, fp32 in/out.
// out[b,c] = sum_s softmax_s( tanh(x@W1+b1)@w2 )[b,s] * x[b,s,c]   (b2 shift-invariant)
//
// R9: wave-autonomous design. Each wave owns 16 rows: stages its own 16KB via
// global_load_lds (per-lane pre-swizzled source), ONE vmcnt(0), then computes
// 16x128x256 GEMM with ZERO barriers (16KB/wave held in flight through the
// stall -> 8 waves/CU keep ~128KB outstanding -> HBM saturated). Weighted sum
// reads x back from the LDS tile (no global re-read). Block = 2 waves (BM=32).

typedef __attribute__((ext_vector_type(8))) short short8;
typedef __attribute__((ext_vector_type(4))) float f32x4;
typedef unsigned short u16;

constexpr int Bb = 32;
constexpr int Ss = 8192;
constexpr int Cc = 256;
constexpr int MIDm = 128;
constexpr int BM = 32;               // rows per block = 2 waves x 16
constexpr int NBLK = Bb * Ss / BM;   // 8192
constexpr int BPB = Ss / BM;         // 256 partials per batch

__device__ __forceinline__ u16 f2bf(float f) {
  return __builtin_bit_cast(u16, __float2bfloat16(f));   // RNE
}

// ---- one-time prep: W fragments, frag-major ----
// FB[(kc*8+nt)*64 + lane] -> 8 bf16 (16B):
//   n = nt*16 + (lane&15),  k = kc*32 + (lane>>4)*8 + e
__global__ __launch_bounds__(256) void wprep_kernel(
    const float* __restrict__ W1, u16* __restrict__ FB)
{
  const int t    = blockIdx.x * 256 + threadIdx.x;   // 0..4095
  const int lane = t & 63;
  const int nt   = (t >> 6) & 7;
  const int kc   = (t >> 9) & 7;
  const int n    = nt * 16 + (lane & 15);
  const int k0   = kc * 32 + (lane >> 4) * 8;
  union { u16 v[8]; short8 s; } u;
  #pragma unroll
  for (int e = 0; e < 8; ++e) u.v[e] = f2bf(W1[(size_t)(k0 + e) * MIDm + n]);
  *(short8*)(FB + (size_t)t * 8) = u.s;
}

// ---- fused: per-wave DMA + barrier-free GEMM -> softmax -> LDS weighted sum ----
__global__ __launch_bounds__(128, 2) void fused_kernel(
    const float* __restrict__ x, const u16* __restrict__ FB,
    const float* __restrict__ b1, const float* __restrict__ w2,
    float* __restrict__ oPart, float* __restrict__ mPart, float* __restrict__ lPart)
{
  __shared__ __align__(16) char tile[2 * 16 * 1024];   // 32KB: wave w rows at w*16KB
  __shared__ float sScore[BM];
  __shared__ float sP[BM];
  __shared__ float sO[2][Cc];
  __shared__ float sML[2];

  const int tid  = threadIdx.x;
  const int lane = tid & 63;
  const int w    = tid >> 6;        // wave 0/1
  const int q    = lane >> 4;       // k-group 0..3
  const int ln   = lane & 15;       // row within wave's 16
  const int row0 = blockIdx.x * BM;
  const int wrow0 = row0 + w * 16;

  char* ldsw = tile + w * 16384;

  // ---- stage this wave's 16 rows (16 x 1KB DMA). Per-lane source pre-swizzled:
  // LDS byte l*16 of row i holds global bytes (l*16)^((i&7)<<4) of that row.
  {
    const char* xb = (const char*)x + (size_t)wrow0 * 1024;
    #pragma unroll
    for (int i = 0; i < 16; ++i) {
      const char* src = xb + (size_t)i * 1024 + ((lane * 16) ^ ((i & 7) << 4));
      __builtin_amdgcn_global_load_lds(
          (const __attribute__((address_space(1))) void*)src,
          (__attribute__((address_space(3))) void*)(ldsw + i * 1024),
          16, 0, 0);
    }
  }

  // acc[nt] over N=128, init with b1
  f32x4 acc[8];
  #pragma unroll
  for (int nt = 0; nt < 8; ++nt) {
    float bj = b1[nt * 16 + ln];
    acc[nt][0] = bj; acc[nt][1] = bj; acc[nt][2] = bj; acc[nt][3] = bj;
  }

  short8 Bf[2][8];   // ping-pong W fragments (L2-hot FB)
  #define LDB(ph, kc_)                                                        \
    { _Pragma("unroll")                                                       \
      for (int nt = 0; nt < 8; ++nt)                                          \
        Bf[ph][nt] = *(const short8*)(FB + ((size_t)((kc_) * 8 + nt) * 64 + lane) * 8); }

  LDB(0, 0)

  // single wait: own DMAs (and B0) landed. Fence so ds_reads can't hoist.
  __builtin_amdgcn_sched_barrier(0);
  asm volatile("s_waitcnt vmcnt(0)" ::: "memory");
  __builtin_amdgcn_sched_barrier(0);

  const int sw = (ln & 7) << 4;
  const char* abase = ldsw + ln * 1024;

  #pragma unroll
  for (int kc = 0; kc < 8; ++kc) {
    const int ph = kc & 1;
    if (kc < 7) LDB(1 - ph, kc + 1)
    const int off = kc * 128 + q * 32;
    float4 lo = *(const float4*)(abase + (off ^ sw));
    float4 hi = *(const float4*)(abase + ((off + 16) ^ sw));
    union { u16 v[8]; short8 s8; } t8;
    t8.v[0] = f2bf(lo.x); t8.v[1] = f2bf(lo.y); t8.v[2] = f2bf(lo.z); t8.v[3] = f2bf(lo.w);
    t8.v[4] = f2bf(hi.x); t8.v[5] = f2bf(hi.y); t8.v[6] = f2bf(hi.z); t8.v[7] = f2bf(hi.w);
    #pragma unroll
    for (int nt = 0; nt < 8; ++nt)
      acc[nt] = __builtin_amdgcn_mfma_f32_16x16x32_bf16(t8.s8, Bf[ph][nt], acc[nt], 0, 0, 0);
  }

  // ---- scores: score[row] = sum_n tanh(h)*w2[n]; rows q*4+r, reduce over ln ----
  float w2v[8];
  #pragma unroll
  for (int nt = 0; nt < 8; ++nt) w2v[nt] = w2[nt * 16 + ln];

  float p[4] = {0.f, 0.f, 0.f, 0.f};
  #pragma unroll
  for (int nt = 0; nt < 8; ++nt)
    #pragma unroll
    for (int r = 0; r < 4; ++r)
      p[r] += (1.0f - 2.0f / (__expf(2.0f * acc[nt][r]) + 1.0f)) * w2v[nt];

  #pragma unroll
  for (int off = 1; off < 16; off <<= 1)
    #pragma unroll
    for (int r = 0; r < 4; ++r) p[r] += __shfl_xor(p[r], off);

  if (ln == 0) {
    #pragma unroll
    for (int r = 0; r < 4; ++r) sScore[w * 16 + q * 4 + r] = p[r];
  }
  __syncthreads();

  // ---- block softmax partials over 32 rows (wave 0) ----
  if (w == 0) {
    float v = (lane < BM) ? sScore[lane] : -3.4e38f;
    float m = v;
    #pragma unroll
    for (int off = 1; off < 64; off <<= 1) m = fmaxf(m, __shfl_xor(m, off));
    float e = (lane < BM) ? __expf(v - m) : 0.f;
    float s = e;
    #pragma unroll
    for (int off = 1; off < 64; off <<= 1) s += __shfl_xor(s, off);
    if (lane < BM) sP[lane] = e;
    if (lane == 0) { sML[0] = m; sML[1] = s; }
  }
  __syncthreads();

  // ---- weighted sum from LDS tile: o[c] = sum_i sP[row] * x[row][c] ----
  float4 o = make_float4(0.f, 0.f, 0.f, 0.f);
  #pragma unroll
  for (int i = 0; i < 16; ++i) {
    float pw = sP[w * 16 + i];
    float4 xv = *(const float4*)(ldsw + i * 1024 + ((lane * 16) ^ ((i & 7) << 4)));
    o.x = fmaf(pw, xv.x, o.x);
    o.y = fmaf(pw, xv.y, o.y);
    o.z = fmaf(pw, xv.z, o.z);
    o.w = fmaf(pw, xv.w, o.w);
  }
  *(float4*)&sO[w][lane * 4] = o;
  __syncthreads();

  {
    const int c0 = tid, c1 = tid + 128;
    float a0 = sO[0][c0] + sO[1][c0];
    float a1 = sO[0][c1] + sO[1][c1];
    float* op = oPart + (size_t)blockIdx.x * Cc;
    op[c0] = a0;
    op[c1] = a1;
  }
  if (tid == 0) { mPart[blockIdx.x] = sML[0]; lPart[blockIdx.x] = sML[1]; }
}

// ---- combine 256 partials per batch (deterministic) ----
__global__ __launch_bounds__(256) void combine_kernel(
    const float* __restrict__ oPart, const float* __restrict__ mPart,
    const float* __restrict__ lPart, float* __restrict__ out)
{
  const int b = blockIdx.x;
  const int t = threadIdx.x;
  float M = -3.4e38f;
  for (int k = 0; k < BPB; ++k) M = fmaxf(M, mPart[b * BPB + k]);
  float num = 0.f, den = 0.f;
  for (int k = 0; k < BPB; ++k) {
    float wgt = __expf(mPart[b * BPB + k] - M);
    den += wgt * lPart[b * BPB + k];
    num = fmaf(wgt, oPart[(size_t)(b * BPB + k) * Cc + t], num);
  }
  out[b * Cc + t] = num / den;
}

extern "C" void kernel_launch(void* const* d_in, const int* in_sizes, int n_in,
                              void* d_out, int out_size, void* d_ws, size_t ws_size,
                              hipStream_t stream)
{
  const float* x  = (const float*)d_in[0];
  const float* W1 = (const float*)d_in[1];
  const float* b1 = (const float*)d_in[2];
  const float* w2 = (const float*)d_in[3];
  // d_in[4] = b2: unused (softmax shift-invariant)
  float* out = (float*)d_out;

  u16*   FB    = (u16*)d_ws;                                          // 64 KB
  float* oPart = (float*)((char*)d_ws + 65536);                       // 8 MB
  float* mPart = (float*)((char*)d_ws + 65536 + 8388608);             // 32 KB
  float* lPart = (float*)((char*)d_ws + 65536 + 8388608 + 32768);     // 32 KB

  wprep_kernel<<<16, 256, 0, stream>>>(W1, FB);
  fused_kernel<<<NBLK, 128, 0, stream>>>(x, FB, b1, w2, oPart, mPart, lPart);
  combine_kernel<<<Bb, Cc, 0, stream>>>(oPart, mPart, lPart, out);
}

// Round 10
// 95.443 us; speedup vs baseline: 1.1742x; 1.1742x over previous
//
#include <hip/hip_runtime.h>
#include <hip/hip_bf16.h>

// AttentivePooling: B=32, S=8192, C=256, MID=128, fp32 in/out.
// out[b,c] = sum_s softmax_s( tanh(x@W1+b1)@w2 )[b,s] * x[b,s,c]   (b2 shift-invariant)
//
// R10: burst-issue design. Per wave (16 rows): A loaded straight to VGPRs via
// asm-volatile global_load_dwordx4 (rolling 4-chunk window, compiler can't
// sink), consumed with exact counted s_waitcnt vmcnt(N). B staged ONCE per
// block (64KB LDS DMA, shared by 8 waves). GEMM region contains no other vmem
// (b1 deferred to epilogue) and ZERO barriers -> every wave keeps loads in
// flight continuously; 16 waves/CU => ~64-128KB/CU outstanding.

typedef __attribute__((ext_vector_type(8))) short short8;
typedef __attribute__((ext_vector_type(4))) float f32x4;
typedef unsigned short u16;

constexpr int Bb = 32;
constexpr int Ss = 8192;
constexpr int Cc = 256;
constexpr int MIDm = 128;
constexpr int BM = 128;              // 8 waves x 16 rows
constexpr int NBLK = Bb * Ss / BM;   // 2048
constexpr int BPB = Ss / BM;         // 64

__device__ __forceinline__ u16 f2bf(float f) {
  return __builtin_bit_cast(u16, __float2bfloat16(f));   // RNE
}

// ---- one-time prep: W fragments, frag-major ----
// FB[(kc*8+nt)*64 + lane] -> 8 bf16 (16B): n = nt*16+(lane&15), k = kc*32+(lane>>4)*8+e
__global__ __launch_bounds__(256) void wprep_kernel(
    const float* __restrict__ W1, u16* __restrict__ FB)
{
  const int t    = blockIdx.x * 256 + threadIdx.x;   // 0..4095
  const int lane = t & 63;
  const int nt   = (t >> 6) & 7;
  const int kc   = (t >> 9) & 7;
  const int n    = nt * 16 + (lane & 15);
  const int k0   = kc * 32 + (lane >> 4) * 8;
  union { u16 v[8]; short8 s; } u;
  #pragma unroll
  for (int e = 0; e < 8; ++e) u.v[e] = f2bf(W1[(size_t)(k0 + e) * MIDm + n]);
  *(short8*)(FB + (size_t)t * 8) = u.s;
}

// ---- fused: burst-issue GEMM -> block softmax -> weighted x partial ----
__global__ __launch_bounds__(512, 4) void fused_kernel(
    const float* __restrict__ x, const u16* __restrict__ FB,
    const float* __restrict__ b1, const float* __restrict__ w2,
    float* __restrict__ oPart, float* __restrict__ mPart, float* __restrict__ lPart)
{
  __shared__ __align__(16) char smem[65536];   // B fragments (64KB); epilogue overlays

  const int tid  = threadIdx.x;
  const int lane = tid & 63;
  const int w    = tid >> 6;        // wave 0..7, owns rows w*16..w*16+15
  const int q    = lane >> 4;       // k-group / output row-group
  const int ln   = lane & 15;       // row within wave tile / output col
  const int row0 = blockIdx.x * BM;

  // ---- issue B DMA: 64KB linear, 8 insts/thread (dest = wave-uniform + lane*16) ----
  {
    const char* src = (const char*)FB + (size_t)tid * 16;
    #pragma unroll
    for (int i = 0; i < 8; ++i) {
      __builtin_amdgcn_global_load_lds(
          (const __attribute__((address_space(1))) void*)(src + (size_t)i * 8192),
          (__attribute__((address_space(3))) void*)(smem + i * 8192 + tid * 16),
          16, 0, 0);
    }
  }
  __builtin_amdgcn_sched_barrier(0);   // pin: B issued before A burst

  // ---- A: per-lane base, rolling 4-chunk asm-load window ----
  const char* pA = (const char*)x + ((size_t)(row0 + w * 16 + ln) * Cc + q * 8) * 4;

  f32x4 rA[4][2];
  #define ISSUEA(slot, kc_)                                                         \
    {                                                                               \
      asm volatile("global_load_dwordx4 %0, %1, off"                                \
                   : "=&v"(rA[slot][0]) : "v"(pA + (kc_) * 128) : "memory");        \
      asm volatile("global_load_dwordx4 %0, %1, off"                                \
                   : "=&v"(rA[slot][1]) : "v"(pA + (kc_) * 128 + 16) : "memory");   \
    }

  ISSUEA(0, 0) ISSUEA(1, 1) ISSUEA(2, 2) ISSUEA(3, 3)

  // wait: vmcnt(6) -> oldest 10 of 16 landed = all 8 B-DMA + A-chunk0
  asm volatile("s_waitcnt vmcnt(6)" ::: "memory");
  __builtin_amdgcn_sched_barrier(0);
  __builtin_amdgcn_s_barrier();        // B visible block-wide
  __builtin_amdgcn_sched_barrier(0);

  f32x4 acc[8];
  #pragma unroll
  for (int nt = 0; nt < 8; ++nt) { acc[nt][0] = 0.f; acc[nt][1] = 0.f; acc[nt][2] = 0.f; acc[nt][3] = 0.f; }

  // ---- GEMM: no barriers; only counted A-waits. (No other vmem in this region!)
  #pragma unroll
  for (int kc = 0; kc < 8; ++kc) {
    asm volatile("s_waitcnt vmcnt(%c0)" :: "i"((kc <= 4) ? 6 : (14 - 2 * kc)) : "memory");
    __builtin_amdgcn_sched_barrier(0);

    const int slot = kc & 3;
    union { u16 v[8]; short8 s8; } t8;
    t8.v[0] = f2bf(rA[slot][0][0]); t8.v[1] = f2bf(rA[slot][0][1]);
    t8.v[2] = f2bf(rA[slot][0][2]); t8.v[3] = f2bf(rA[slot][0][3]);
    t8.v[4] = f2bf(rA[slot][1][0]); t8.v[5] = f2bf(rA[slot][1][1]);
    t8.v[6] = f2bf(rA[slot][1][2]); t8.v[7] = f2bf(rA[slot][1][3]);
    const short8 af = t8.s8;

    if (kc < 4) ISSUEA(slot, kc + 4)   // refill freed slot; stays in flight ~4 iters

    #pragma unroll
    for (int nt = 0; nt < 8; ++nt) {
      short8 bf = *(const short8*)(smem + (((kc * 8 + nt) * 64 + lane) << 4));
      acc[nt] = __builtin_amdgcn_mfma_f32_16x16x32_bf16(af, bf, acc[nt], 0, 0, 0);
    }
  }

  __syncthreads();   // all B reads done -> overlay epilogue arrays on smem

  float* sScore = (float*)smem;             // [128]
  float* sP     = (float*)(smem + 512);     // [128]
  float* sO     = (float*)(smem + 1024);    // [8][256]
  float* sML    = (float*)(smem + 9216);    // m, l

  // ---- scores: h = acc + b1; score[row] = sum_n tanh(h)*w2[n] ----
  float b1v[8], w2v[8];
  #pragma unroll
  for (int nt = 0; nt < 8; ++nt) { b1v[nt] = b1[nt * 16 + ln]; w2v[nt] = w2[nt * 16 + ln]; }

  float p[4] = {0.f, 0.f, 0.f, 0.f};
  #pragma unroll
  for (int nt = 0; nt < 8; ++nt)
    #pragma unroll
    for (int r = 0; r < 4; ++r) {
      float h = acc[nt][r] + b1v[nt];
      p[r] += (1.0f - 2.0f / (__expf(2.0f * h) + 1.0f)) * w2v[nt];
    }
  #pragma unroll
  for (int off = 1; off < 16; off <<= 1)
    #pragma unroll
    for (int r = 0; r < 4; ++r) p[r] += __shfl_xor(p[r], off);

  if (ln == 0) {
    #pragma unroll
    for (int r = 0; r < 4; ++r) sScore[w * 16 + q * 4 + r] = p[r];
  }
  __syncthreads();

  // ---- block softmax over 128 rows (wave 0) ----
  if (w == 0) {
    float a = sScore[lane], b = sScore[lane + 64];
    float m = fmaxf(a, b);
    #pragma unroll
    for (int off = 1; off < 64; off <<= 1) m = fmaxf(m, __shfl_xor(m, off));
    float e0 = __expf(a - m), e1 = __expf(b - m);
    sP[lane] = e0; sP[lane + 64] = e1;
    float s = e0 + e1;
    #pragma unroll
    for (int off = 1; off < 64; off <<= 1) s += __shfl_xor(s, off);
    if (lane == 0) { sML[0] = m; sML[1] = s; }
  }
  __syncthreads();

  // ---- weighted x partial: each wave its 16 rows, re-read from L2 ----
  const float* xo = x + (size_t)(row0 + w * 16) * Cc + lane * 4;
  float4 o = make_float4(0.f, 0.f, 0.f, 0.f);
  #pragma unroll 8
  for (int r = 0; r < 16; ++r) {
    float pw = sP[w * 16 + r];
    float4 xv = *(const float4*)(xo + (size_t)r * Cc);
    o.x = fmaf(pw, xv.x, o.x);
    o.y = fmaf(pw, xv.y, o.y);
    o.z = fmaf(pw, xv.z, o.z);
    o.w = fmaf(pw, xv.w, o.w);
  }
  *(float4*)&sO[w * Cc + lane * 4] = o;
  __syncthreads();

  if (tid < Cc) {
    float oc = 0.f;
    #pragma unroll
    for (int i = 0; i < 8; ++i) oc += sO[i * Cc + tid];
    oPart[(size_t)blockIdx.x * Cc + tid] = oc;
  }
  if (tid == 0) { mPart[blockIdx.x] = sML[0]; lPart[blockIdx.x] = sML[1]; }
}

// ---- combine 64 block partials per batch (deterministic) ----
__global__ __launch_bounds__(256) void combine_kernel(
    const float* __restrict__ oPart, const float* __restrict__ mPart,
    const float* __restrict__ lPart, float* __restrict__ out)
{
  const int b = blockIdx.x;
  const int t = threadIdx.x;
  float M = -3.4e38f;
  for (int k = 0; k < BPB; ++k) M = fmaxf(M, mPart[b * BPB + k]);
  float num = 0.f, den = 0.f;
  for (int k = 0; k < BPB; ++k) {
    float wgt = __expf(mPart[b * BPB + k] - M);
    den += wgt * lPart[b * BPB + k];
    num = fmaf(wgt, oPart[(size_t)(b * BPB + k) * Cc + t], num);
  }
  out[b * Cc + t] = num / den;
}

extern "C" void kernel_launch(void* const* d_in, const int* in_sizes, int n_in,
                              void* d_out, int out_size, void* d_ws, size_t ws_size,
                              hipStream_t stream)
{
  const float* x  = (const float*)d_in[0];
  const float* W1 = (const float*)d_in[1];
  const float* b1 = (const float*)d_in[2];
  const float* w2 = (const float*)d_in[3];
  // d_in[4] = b2: unused (softmax shift-invariant)
  float* out = (float*)d_out;

  u16*   FB    = (u16*)d_ws;                                  // 64 KB frag-major W
  float* oPart = (float*)((char*)d_ws + 65536);               // 2 MB
  float* mPart = (float*)((char*)d_ws + 65536 + 2097152);     // 8 KB
  float* lPart = (float*)((char*)d_ws + 65536 + 2097152 + 8192);

  wprep_kernel<<<16, 256, 0, stream>>>(W1, FB);
  fused_kernel<<<NBLK, 512, 0, stream>>>(x, FB, b1, w2, oPart, mPart, lPart);
  combine_kernel<<<Bb, Cc, 0, stream>>>(oPart, mPart, lPart, out);
}